// Round 15
// baseline (47.325 us; speedup 1.0000x reference)
//
#include <hip/hip_runtime.h>

// Lucas-Kanade optical flow v15 = v14 with the scan loop ROLLED (#pragma
// unroll 1) -- single-variable experiment for the instruction-fetch theory.
// Evidence: all plateau kernels (v4..v14, ~31-34us) fully unroll 18-30
// steps x ~100 insts = 20-30KB straight-line code per template body,
// streamed once per wave (zero I-cache reuse). VALUBusy ~25% with clean
// data-side counters = issue stalled on I-fetch. Rolled body ~1.5KB fits
// I-cache. Everything else identical to v14: RB=16, LDS exit ring (zero
// exit re-reads), 6-deep enter prefetch, 2 cols/lane, XCD swizzle,
// prefix-doubling emit, no occupancy attrs (they pin VGPR=64 and spill).
// Derivatives unscaled (8fx, 8fy, 4ft); exact x2 rescale folded into u,v.

constexpr int IH  = 2048;
constexpr int IW  = 2048;
constexpr int RAD = 7;
constexpr int WIN = 15;
constexpr int NT  = 64;               // 1 wave per block
constexpr int SW  = 112;              // output columns per block (2/lane, lanes 0..55)
constexpr int RB  = 16;               // output rows per block
constexpr int SCAN = RB + WIN - 1;    // 30 steps; entering product rows r0-7 .. r0+22
constexpr int NSTRIP = 19;            // 19*112 = 2128 >= 2048
constexpr int NBAND  = IH / RB;       // 128
constexpr int NXCD   = 8;
constexpr int CHUNK  = NBAND / NXCD;  // 16 bands per XCD per strip
constexpr int RING   = 16;            // LDS ring rows (>= WIN+1)

// Per-row derived terms for this lane's 2 columns: sp = prev+next, dt = next-prev.
struct Row { float sp0, sp1, dt0, dt1; };

template<bool YE>
__device__ __forceinline__ Row load_row(const float* __restrict__ P,
                                        const float* __restrict__ N,
                                        int row, int pcb, bool lload) {
    if constexpr (YE) row = row < 0 ? 0 : (row > IH - 1 ? IH - 1 : row);
    float2 q = make_float2(0.f, 0.f), r = q;
    if (lload) {                       // false only for OOB lanes on edge strips
        const size_t off = (size_t)row * IW + pcb;
        q = *reinterpret_cast<const float2*>(P + off);   // 8B aligned (pcb even)
        r = *reinterpret_cast<const float2*>(N + off);
    }
    Row R;
    R.sp0 = q.x + r.x; R.dt0 = r.x - q.x;
    R.sp1 = q.y + r.y; R.dt1 = r.y - q.y;
    return R;
}

// Add (SUB=false) or remove (SUB=true) product-row pair (A=row r, B=row r+1).
// Lane handles product cols pcb, pcb+1; col pcb+2 terms come from lane t+1.
template<bool SUB, bool XE>
__device__ __forceinline__ void accum(float V[5][2], const Row& A, const Row& B,
                                      int t, bool ok, bool rep2) {
    const float g0 = A.sp0 + B.sp0, g1 = A.sp1 + B.sp1;  // -> 8*fx via horiz diff
    const float m0 = B.sp0 - A.sp0, m1 = B.sp1 - A.sp1;  // -> 8*fy
    const float e0 = A.dt0 + B.dt0, e1 = A.dt1 + B.dt1;  // -> 4*ft
    float g2 = __shfl(g0, t + 1);
    float m2 = __shfl(m0, t + 1);
    float e2 = __shfl(e0, t + 1);
    if constexpr (XE) {                 // right edge: replicate last column
        g2 = rep2 ? g1 : g2; m2 = rep2 ? m1 : m2; e2 = rep2 ? e1 : e2;
    }
    float fx0 = g1 - g0, fy0 = m0 + m1, ft0 = e0 + e1;
    float fx1 = g2 - g1, fy1 = m1 + m2, ft1 = e1 + e2;
    if constexpr (XE) {                 // zero products outside the image
        fx0 = ok ? fx0 : 0.f; fy0 = ok ? fy0 : 0.f; ft0 = ok ? ft0 : 0.f;
        fx1 = ok ? fx1 : 0.f; fy1 = ok ? fy1 : 0.f; ft1 = ok ? ft1 : 0.f;
    }
    if constexpr (!SUB) {
        V[0][0] += fx0 * fx0; V[1][0] += fx0 * fy0; V[2][0] += fy0 * fy0;
        V[3][0] += fx0 * ft0; V[4][0] += fy0 * ft0;
        V[0][1] += fx1 * fx1; V[1][1] += fx1 * fy1; V[2][1] += fy1 * fy1;
        V[3][1] += fx1 * ft1; V[4][1] += fy1 * ft1;
    } else {
        V[0][0] -= fx0 * fx0; V[1][0] -= fx0 * fy0; V[2][0] -= fy0 * fy0;
        V[3][0] -= fx0 * ft0; V[4][0] -= fy0 * ft0;
        V[0][1] -= fx1 * fx1; V[1][1] -= fx1 * fy1; V[2][1] -= fy1 * fy1;
        V[3][1] -= fx1 * ft1; V[4][1] -= fy1 * ft1;
    }
}

template<bool XE, bool YE>
__device__ __forceinline__ void lk_body(const float* __restrict__ P,
                                        const float* __restrict__ N,
                                        float* __restrict__ out,
                                        float4* __restrict__ ring,   // LDS [RING][64]
                                        int c0, int r0, int t) {
    const int pcb = c0 - 8 + 2 * t;     // lane's first tracked product column (even)
    bool ok = true, rep2 = false;
    if constexpr (XE) {
        ok   = ((unsigned)pcb < (unsigned)IW);   // both owned cols in image
        rep2 = (pcb + 2 >= IW) && ok;            // col pcb+2 replicates pcb+1
    }
    const bool lload = ok;              // interior strips: uniformly true

    float V[5][2] = {};

    // entering pipeline E0..E5 = rows r0-7 .. r0-2 (use distance 5-6 steps)
    Row E0 = load_row<YE>(P, N, r0 - 7, pcb, lload);
    Row E1 = load_row<YE>(P, N, r0 - 6, pcb, lload);
    Row E2 = load_row<YE>(P, N, r0 - 5, pcb, lload);
    Row E3 = load_row<YE>(P, N, r0 - 4, pcb, lload);
    Row E4 = load_row<YE>(P, N, r0 - 3, pcb, lload);
    Row E5 = load_row<YE>(P, N, r0 - 2, pcb, lload);
    Row XA = E0, XB = E0;               // exiting pair (fed from the LDS ring)

    #pragma unroll 1                    // ROLLED: ~1.5KB body, I-cache resident
    for (int sr = 0; sr < SCAN; ++sr) {
        const int pr = r0 - RAD + sr;   // entering product row

        // deep prefetch: row pr+6 (last needed image row = r0+23 -> sr <= 24)
        Row nE;
        const bool doE = (sr <= 24);
        if (doE) nE = load_row<YE>(P, N, pr + 6, pcb, lload);

        // ring: save entering row pr; recover exiting row pr-14.
        // slot sr%16 holds row r0-7+sr; read (sr-14)%16 = row pr-14 (written
        // 14 steps ago, overwritten at sr+2 -> safe).
        ring[(sr & 15) * NT + t] = make_float4(E0.sp0, E0.sp1, E0.dt0, E0.dt1);
        if (sr >= 14) {
            XA = XB;
            const float4 rr = ring[((sr - 14) & 15) * NT + t];
            XB.sp0 = rr.x; XB.sp1 = rr.y; XB.dt0 = rr.z; XB.dt1 = rr.w;
        }

        // vertical running box sum: add entering product row (rows pr, pr+1)
        bool enter_ok = true;
        if constexpr (YE) enter_ok = (pr >= 0) && (pr < IH);
        if (enter_ok) accum<false, XE>(V, E0, E1, t, ok, rep2);

        // subtract exiting product row (rows pr-15 = XA, pr-14 = XB)
        if (sr >= WIN) {
            bool exit_ok = true;
            if constexpr (YE) exit_ok = (pr - WIN) >= 0;
            if (exit_ok) accum<true, XE>(V, XA, XB, t, ok, rep2);
        }

        // emit output row i = r0 + sr - 14 (V holds product rows [pr-14, pr])
        if (sr >= WIN - 1) {
            float a0[5], a1[5];
            #pragma unroll
            for (int p = 0; p < 5; ++p) {
                const float Pg = V[p][0] + V[p][1];        // pair sum (2 cols)
                float S = Pg + __shfl(Pg, t + 1);
                S += __shfl(S, t + 2);
                S += __shfl(S, t + 4);                     // cols pcb..pcb+15
                const float q0 = __shfl(V[p][0], t + 8);   // col pcb+16
                a0[p] = S - V[p][0];                       // cols pcb+1 .. pcb+15
                a1[p] = (S - Pg) + q0;                     // cols pcb+2 .. pcb+16
            }
            const float det0 = a0[0] * a0[2] - a0[1] * a0[1];
            const float rd0  = __builtin_amdgcn_rcpf(det0) * 2.0f;  // fold scale
            const bool  k0   = (det0 != 0.f);
            const float det1 = a1[0] * a1[2] - a1[1] * a1[1];
            const float rd1  = __builtin_amdgcn_rcpf(det1) * 2.0f;
            const bool  k1   = (det1 != 0.f);
            float2 qu, qv;
            qu.x = k0 ? (a0[2] * a0[3] - a0[1] * a0[4]) * rd0 : 0.f;
            qv.x = k0 ? (a0[0] * a0[4] - a0[1] * a0[3]) * rd0 : 0.f;
            qu.y = k1 ? (a1[2] * a1[3] - a1[1] * a1[4]) * rd1 : 0.f;
            qv.y = k1 ? (a1[0] * a1[4] - a1[1] * a1[3]) * rd1 : 0.f;

            const int i  = r0 + sr - (WIN - 1);
            const int x0 = c0 + 2 * t;
            if ((2 * t < SW) && (x0 < IW)) {   // x0 even -> x0+1 in range too
                *reinterpret_cast<float2*>(out + (size_t)i * IW + x0) = qu;
                *reinterpret_cast<float2*>(out + (size_t)IH * IW + (size_t)i * IW + x0) = qv;
            }
        }

        // slide (explicit moves; no runtime-indexed register arrays)
        E0 = E1; E1 = E2; E2 = E3; E3 = E4; E4 = E5; if (doE) E5 = nE;
    }
}

__global__ __launch_bounds__(NT)   // NO occupancy attrs: they pin VGPR=64 and spill
void lk_kernel(const float* __restrict__ Pimg, const float* __restrict__ Nimg,
               float* __restrict__ out) {
    // per-wave LDS ring: 16 rows x 64 lanes x 16B = 16 KB. Lane slot stride
    // 16B -> max 2-way bank aliasing on b128 (free per m136).
    __shared__ float4 ring[RING * NT];

    // XCD-chunked swizzle: XCD (bid&7) owns 16 contiguous 16-row bands of one
    // strip -> enter-halo re-reads across adjacent bands hit the local L2.
    const int bid   = blockIdx.x;
    const int xcd   = bid & 7;
    const int idx   = bid >> 3;               // 0..303
    const int strip = idx / CHUNK;            // 0..18
    const int pos   = idx % CHUNK;
    const int band  = xcd * CHUNK + pos;      // 0..127
    const int c0 = strip * SW;
    const int r0 = band * RB;
    const int t  = threadIdx.x;
    const bool xe = (strip == 0) || (strip == NSTRIP - 1);
    // rows touched: [r0-7, r0+23]; in-bounds iff 1 <= band <= NBAND-2
    const bool ye = (band == 0) || (band == NBAND - 1);
    if (!xe && !ye)      lk_body<false, false>(Pimg, Nimg, out, ring, c0, r0, t);
    else if (xe && !ye)  lk_body<true,  false>(Pimg, Nimg, out, ring, c0, r0, t);
    else if (!xe)        lk_body<false, true >(Pimg, Nimg, out, ring, c0, r0, t);
    else                 lk_body<true,  true >(Pimg, Nimg, out, ring, c0, r0, t);
}

extern "C" void kernel_launch(void* const* d_in, const int* in_sizes, int n_in,
                              void* d_out, int out_size, void* d_ws, size_t ws_size,
                              hipStream_t stream) {
    (void)in_sizes; (void)n_in; (void)d_ws; (void)ws_size; (void)out_size;
    const float* prev = (const float*)d_in[0];
    const float* nxt  = (const float*)d_in[1];
    float* out        = (float*)d_out;
    dim3 grid(NSTRIP * NBAND);                // 2432 one-wave blocks
    dim3 block(NT);
    hipLaunchKernelGGL(lk_kernel, grid, block, 0, stream, prev, nxt, out);
}

// Round 16
// 33.093 us; speedup vs baseline: 1.4301x; 1.4301x over previous
//
#include <hip/hip_runtime.h>

// Lucas-Kanade optical flow v16: 8-wave shared LDS tile, minimal fabric demand.
// Round-15 falsifications: I-cache (rolled = worse), HBM BW (FETCH=25MB,
// inputs L3-resident). Surviving model: L2/L3-fabric service band -- all
// plateau kernels demand 4.5-7 TB/s from cache. v16: 512-thread blocks stage
// a 48x128 sp/dt tile once (49KB LDS, float4, one barrier); 8 waves scan 4
// output rows each entirely from LDS. Global demand 60MB (~1.9TB/s), waves
// 9728 (24/CU at 3 blocks/CU) -> both low demand AND latency coverage.
// 2 cols/lane, prefix-doubling emit, XCD swizzle, full unroll, no occupancy
// attrs. Derivatives unscaled (8fx,8fy,4ft); exact x2 rescale folded in u,v.

constexpr int IH  = 2048;
constexpr int IW  = 2048;
constexpr int RAD = 7;
constexpr int WIN = 15;
constexpr int NT  = 512;              // 8 waves per block
constexpr int SW  = 112;              // output cols per block (2/lane, lanes 0..55)
constexpr int RBW = 4;                // output rows per wave
constexpr int TH  = 32;               // output rows per block (8 waves x 4)
constexpr int SROWS = TH + WIN + 1;   // 48 staged image rows: R-7 .. R+40
constexpr int SCAN  = RBW + WIN - 1;  // 18 steps per wave
constexpr int NSTRIP = 19;            // 19*112 = 2128 >= 2048
constexpr int NBANDS = IH / TH;       // 64
constexpr int NXCD   = 8;
constexpr int CHUNK  = NBANDS / NXCD; // 8 bands per XCD per strip

__device__ __forceinline__ int clampi(int v, int lo, int hi) {
    return v < lo ? lo : (v > hi ? hi : v);
}

struct Row { float sp0, sp1, dt0, dt1; };

// Add (SUB=false) or remove (SUB=true) product-row pair (A=row r, B=row r+1).
template<bool SUB, bool XE>
__device__ __forceinline__ void accum(float V[5][2], const Row& A, const Row& B,
                                      int t, bool ok, bool rep2) {
    const float g0 = A.sp0 + B.sp0, g1 = A.sp1 + B.sp1;  // -> 8*fx via horiz diff
    const float m0 = B.sp0 - A.sp0, m1 = B.sp1 - A.sp1;  // -> 8*fy
    const float e0 = A.dt0 + B.dt0, e1 = A.dt1 + B.dt1;  // -> 4*ft
    float g2 = __shfl(g0, t + 1);
    float m2 = __shfl(m0, t + 1);
    float e2 = __shfl(e0, t + 1);
    if constexpr (XE) {                 // right edge: replicate last column
        g2 = rep2 ? g1 : g2; m2 = rep2 ? m1 : m2; e2 = rep2 ? e1 : e2;
    }
    float fx0 = g1 - g0, fy0 = m0 + m1, ft0 = e0 + e1;
    float fx1 = g2 - g1, fy1 = m1 + m2, ft1 = e1 + e2;
    if constexpr (XE) {                 // zero products outside the image
        fx0 = ok ? fx0 : 0.f; fy0 = ok ? fy0 : 0.f; ft0 = ok ? ft0 : 0.f;
        fx1 = ok ? fx1 : 0.f; fy1 = ok ? fy1 : 0.f; ft1 = ok ? ft1 : 0.f;
    }
    if constexpr (!SUB) {
        V[0][0] += fx0 * fx0; V[1][0] += fx0 * fy0; V[2][0] += fy0 * fy0;
        V[3][0] += fx0 * ft0; V[4][0] += fy0 * ft0;
        V[0][1] += fx1 * fx1; V[1][1] += fx1 * fy1; V[2][1] += fy1 * fy1;
        V[3][1] += fx1 * ft1; V[4][1] += fy1 * ft1;
    } else {
        V[0][0] -= fx0 * fx0; V[1][0] -= fx0 * fy0; V[2][0] -= fy0 * fy0;
        V[3][0] -= fx0 * ft0; V[4][0] -= fy0 * ft0;
        V[0][1] -= fx1 * fx1; V[1][1] -= fx1 * fy1; V[2][1] -= fy1 * fy1;
        V[3][1] -= fx1 * ft1; V[4][1] -= fy1 * ft1;
    }
}

template<bool XE, bool YE>
__device__ __forceinline__ void scan_body(const float2* __restrict__ sp,
                                          const float2* __restrict__ dt,
                                          float* __restrict__ out,
                                          int c0, int r0, int kb, int t) {
    const int pcb = c0 - 8 + 2 * t;     // lane's first tracked product column
    bool ok = true, rep2 = false;
    if constexpr (XE) {
        ok   = ((unsigned)pcb < (unsigned)IW);
        rep2 = (pcb + 2 >= IW) && ok;
    }

    auto ldrow = [&](int k) -> Row {
        const float2 a = sp[k * 64 + t];
        const float2 b = dt[k * 64 + t];
        Row r; r.sp0 = a.x; r.sp1 = a.y; r.dt0 = b.x; r.dt1 = b.y; return r;
    };

    float V[5][2] = {};
    Row E0 = ldrow(kb), E1 = ldrow(kb + 1), E2 = ldrow(kb + 2);

    #pragma unroll
    for (int sr = 0; sr < SCAN; ++sr) { // fully unrolled (v15: rolled is worse)
        const int pr = r0 - RAD + sr;   // entering product row

        Row nE;
        const bool doE = (sr <= 15);    // last needed stage row = kb+18
        if (doE) nE = ldrow(kb + sr + 3);

        bool enter_ok = true;
        if constexpr (YE) enter_ok = (pr >= 0) && (pr < IH);
        if (enter_ok) accum<false, XE>(V, E0, E1, t, ok, rep2);

        if (sr >= WIN) {
            bool exit_ok = true;
            if constexpr (YE) exit_ok = (pr - WIN) >= 0;
            if (exit_ok) {
                const Row XA = ldrow(kb + sr - 15);
                const Row XB = ldrow(kb + sr - 14);
                accum<true, XE>(V, XA, XB, t, ok, rep2);
            }
        }

        // emit output row i = r0 + sr - 14  (always in [r0, r0+3] c [0,IH))
        if (sr >= WIN - 1) {
            float a0[5], a1[5];
            #pragma unroll
            for (int p = 0; p < 5; ++p) {
                const float Pg = V[p][0] + V[p][1];        // pair sum (2 cols)
                float S = Pg + __shfl(Pg, t + 1);
                S += __shfl(S, t + 2);
                S += __shfl(S, t + 4);                     // cols pcb..pcb+15
                const float q0 = __shfl(V[p][0], t + 8);   // col pcb+16
                a0[p] = S - V[p][0];                       // cols pcb+1 .. pcb+15
                a1[p] = (S - Pg) + q0;                     // cols pcb+2 .. pcb+16
            }
            const float det0 = a0[0] * a0[2] - a0[1] * a0[1];
            const float rd0  = __builtin_amdgcn_rcpf(det0) * 2.0f;  // fold scale
            const bool  k0   = (det0 != 0.f);
            const float det1 = a1[0] * a1[2] - a1[1] * a1[1];
            const float rd1  = __builtin_amdgcn_rcpf(det1) * 2.0f;
            const bool  k1   = (det1 != 0.f);
            float2 qu, qv;
            qu.x = k0 ? (a0[2] * a0[3] - a0[1] * a0[4]) * rd0 : 0.f;
            qv.x = k0 ? (a0[0] * a0[4] - a0[1] * a0[3]) * rd0 : 0.f;
            qu.y = k1 ? (a1[2] * a1[3] - a1[1] * a1[4]) * rd1 : 0.f;
            qv.y = k1 ? (a1[0] * a1[4] - a1[1] * a1[3]) * rd1 : 0.f;

            const int i  = r0 + sr - (WIN - 1);
            const int x0 = c0 + 2 * t;
            if ((2 * t < SW) && (x0 < IW)) {   // x0 even -> x0+1 in range too
                *reinterpret_cast<float2*>(out + (size_t)i * IW + x0) = qu;
                *reinterpret_cast<float2*>(out + (size_t)IH * IW + (size_t)i * IW + x0) = qv;
            }
        }

        E0 = E1; E1 = E2; if (doE) E2 = nE;   // slide (renamed by unroll)
    }
}

__global__ __launch_bounds__(NT)   // no occupancy attrs (they pin VGPR=64 + spill)
void lk_kernel(const float* __restrict__ Pimg, const float* __restrict__ Nimg,
               float* __restrict__ out) {
    // 48 rows x 128 cols sp/dt tile: 49,152B LDS -> 3 blocks/CU (24 waves/CU)
    __shared__ float4 s_sp[SROWS][32];
    __shared__ float4 s_dt[SROWS][32];

    // XCD-chunked swizzle: XCD (bid&7) owns 8 contiguous 32-row bands of one
    // strip -> inter-block halo re-reads hit the local L2. 1216 % 8 == 0.
    const int bid   = blockIdx.x;
    const int xcd   = bid & 7;
    const int idx   = bid >> 3;               // 0..151
    const int strip = idx / CHUNK;            // 0..18
    const int pos   = idx % CHUNK;
    const int band  = xcd * CHUNK + pos;      // 0..63
    const int c0    = strip * SW;
    const int R     = band * TH;              // block's first output row

    // ---- cooperative stage: 48 rows x 128 cols of sp/dt (float4) ----
    {
        const int jq = threadIdx.x & 31;      // col quad (4 cols)
        const int rr = threadIdx.x >> 5;      // 0..15 (16 rows per round)
        const int gc = c0 - 8 + 4 * jq;
        const bool in4 = (gc >= 0) && (gc + 3 < IW);
        #pragma unroll
        for (int k0 = 0; k0 < SROWS; k0 += 16) {
            const int k   = k0 + rr;
            const int row = clampi(R - RAD + k, 0, IH - 1);
            const float* rp = Pimg + (size_t)row * IW;
            const float* rn = Nimg + (size_t)row * IW;
            float4 p, n;
            if (in4) {
                p = *reinterpret_cast<const float4*>(rp + gc);   // 16B aligned
                n = *reinterpret_cast<const float4*>(rn + gc);
            } else {                           // edge strips only
                const int g0 = clampi(gc,     0, IW - 1);
                const int g1 = clampi(gc + 1, 0, IW - 1);
                const int g2 = clampi(gc + 2, 0, IW - 1);
                const int g3 = clampi(gc + 3, 0, IW - 1);
                p = make_float4(rp[g0], rp[g1], rp[g2], rp[g3]);
                n = make_float4(rn[g0], rn[g1], rn[g2], rn[g3]);
            }
            s_sp[k][jq] = make_float4(p.x + n.x, p.y + n.y, p.z + n.z, p.w + n.w);
            s_dt[k][jq] = make_float4(n.x - p.x, n.y - p.y, n.z - p.z, n.w - p.w);
        }
    }
    __syncthreads();

    // ---- barrier-free register scan: wave w owns output rows R+4w .. R+4w+3
    const int wid = threadIdx.x >> 6;         // 0..7
    const int t   = threadIdx.x & 63;
    const int r0  = R + RBW * wid;
    const int kb  = RBW * wid;                // stage index of image row r0-7
    const float2* sp = reinterpret_cast<const float2*>(&s_sp[0][0]);
    const float2* dt = reinterpret_cast<const float2*>(&s_dt[0][0]);
    const bool xe = (strip == 0) || (strip == NSTRIP - 1);
    const bool ye = (band == 0) || (band == NBANDS - 1);
    if (!xe && !ye)      scan_body<false, false>(sp, dt, out, c0, r0, kb, t);
    else if (xe && !ye)  scan_body<true,  false>(sp, dt, out, c0, r0, kb, t);
    else if (!xe)        scan_body<false, true >(sp, dt, out, c0, r0, kb, t);
    else                 scan_body<true,  true >(sp, dt, out, c0, r0, kb, t);
}

extern "C" void kernel_launch(void* const* d_in, const int* in_sizes, int n_in,
                              void* d_out, int out_size, void* d_ws, size_t ws_size,
                              hipStream_t stream) {
    (void)in_sizes; (void)n_in; (void)d_ws; (void)ws_size; (void)out_size;
    const float* prev = (const float*)d_in[0];
    const float* nxt  = (const float*)d_in[1];
    float* out        = (float*)d_out;
    dim3 grid(NSTRIP * NBANDS);               // 1216 blocks x 8 waves = 9728 waves
    dim3 block(NT);
    hipLaunchKernelGGL(lk_kernel, grid, block, 0, stream, prev, nxt, out);
}